// Round 12
// baseline (82.710 us; speedup 1.0000x reference)
//
#include <hip/hip_runtime.h>
#include <stdint.h>
#include <math.h>

#define B_ 32
#define S_ 512
#define H_ 768
#define V_ 30522
#define M_ (B_*S_)   // 16384
#define N1_ 512

typedef __attribute__((ext_vector_type(8))) short bf16x8;
typedef __attribute__((ext_vector_type(4))) float f32x4;

__device__ __forceinline__ float bf2f(unsigned short u){
  union { unsigned int u; float f; } c; c.u = ((unsigned int)u)<<16; return c.f;
}
__device__ __forceinline__ unsigned short f2bf(float f){
  union { float f; unsigned int u; } c; c.f=f;
  unsigned int u = c.u + 0x7FFFu + ((c.u>>16)&1u);
  return (unsigned short)(u>>16);
}
__device__ __forceinline__ bool tbl_get(const void* t, int id, int flag){
  if(flag==1) return ((const int*)t)[id]!=0;
  if(flag==2) return ((const unsigned int*)t)[id]!=0u;   // f32 stored 0.0/1.0
  return ((const unsigned char*)t)[id]!=0;
}
__device__ __forceinline__ void gload_lds16(const void* g, void* l){
  __builtin_amdgcn_global_load_lds(
    (const __attribute__((address_space(1))) void*)g,
    (__attribute__((address_space(3))) void*)l, 16, 0, 0);
}

// ---- K0: blocks 0-31: per-batch mask+scan -> cid/cnt; blocks 32+: weight conversion.
//      Block 32 also zeroes the output (atomic-accumulated by k_tail later in stream order).
__global__ __launch_bounds__(256) void k_prep(const void* __restrict__ in_table,
  const int* __restrict__ ids,
  const float* __restrict__ W1, const float* __restrict__ W2,
  const float* __restrict__ Wa1, const float* __restrict__ Wa2, const float* __restrict__ ba1,
  unsigned short* __restrict__ W1bf, unsigned short* __restrict__ W2bf,
  unsigned short* __restrict__ Wa1bf, float* __restrict__ Wa2p, float* __restrict__ ba1p,
  int* __restrict__ cid, int* __restrict__ cnt, float* __restrict__ out)
{
  const int blk = blockIdx.x;
  const int t = threadIdx.x;
  if(blk < 32){
    __shared__ int sh[512];
    __shared__ int sflag;
    if(t < 64){
      const int v = ((const int*)in_table)[t];
      const unsigned int u = (unsigned int)v;
      const unsigned long long b01 = __ballot(v==0 || v==1);
      const unsigned long long bfl = __ballot(u==0u || u==0x3F800000u);
      if(t==0) sflag = (~b01==0ull) ? 1 : ((~bfl==0ull) ? 2 : 0);
    }
    __syncthreads();
    const int flag = sflag;
    const int m0 = blk*S_ + t, m1 = m0 + 256;
    const int id0 = ids[m0], id1 = ids[m1];
    const int mk0 = ((t!=0) && tbl_get(in_table, id0, flag)) ? 1 : 0;
    const int mk1 = tbl_get(in_table, id1, flag) ? 1 : 0;
    sh[t] = mk0; sh[t+256] = mk1;
    __syncthreads();
    for(int off=1; off<512; off<<=1){
      const int a0 = (t >= off) ? sh[t-off] : 0;
      const int a1 = (t+256 >= off) ? sh[t+256-off] : 0;
      __syncthreads();
      sh[t] += a0; sh[t+256] += a1;
      __syncthreads();
    }
    const int total = sh[511];
    const int r0 = sh[t] - mk0;
    const int r1 = sh[t+256] - mk1;
    if(t >= total)     cid[blk*S_ + t]       = 0;
    if(t+256 >= total) cid[blk*S_ + t + 256] = 0;
    if(mk0) cid[blk*S_ + r0] = id0;
    if(mk1) cid[blk*S_ + r1] = id1;
    if(t==0) cnt[blk] = total;
  } else {
    if(blk == 32 && t < 96) out[t] = 0.f;
    const int g = (blk-32)*256 + t, st = (gridDim.x-32)*256;
    for(int i=g;i<512*H_;i+=st) W1bf[i]=f2bf(W1[i]);
    for(int i=g;i<H_*512;i+=st) W2bf[i]=f2bf(W2[i]);
    for(int i=g;i<128*H_;i+=st) Wa1bf[i] = (i<100*H_)? f2bf(Wa1[i]) : (unsigned short)0;
    if(g < 128){ Wa2p[g] = (g<100)? Wa2[g] : 0.f; ba1p[g] = (g<100)? ba1[g] : 0.f; }
  }
}

// ---- K1: gather-fused MFMA GEMM1: x = relu(table[cid[.]] . W1^T + b1), bf16 out ----
// BM=128; 3-buffer LDS ring, counted vmcnt (never 0 mid-loop), raw s_barrier.
// L=6 loads/thread/STAGE (4 A + 2 B): steady wait = vmcnt(12) = oldest tile only.
__global__ __launch_bounds__(256) void k_gemm1g(
  const float* __restrict__ table, const int* __restrict__ cid,
  const unsigned short* __restrict__ Bw, const float* __restrict__ bias,
  const int* __restrict__ cnt, unsigned short* __restrict__ C)
{
  const int m0 = blockIdx.x << 7;
  if((m0 & (S_-1)) >= cnt[m0 >> 9]) return;
  __shared__ __align__(16) float AsF[3][128*32];
  __shared__ __align__(16) unsigned short Bs[3][128*32];
  const int tid = threadIdx.x;
  const int lane = tid & 63;
  const int wave = tid >> 6;
  const int wr = wave >> 1, wc = wave & 1;
  const int n0 = blockIdx.y << 7;

  const float* gaq[4];
  #pragma unroll
  for(int q=0;q<4;q++){
    const int s = q*256 + tid;
    const int row = s >> 3, ch = s & 7;
    const int sch = ch ^ (row & 7);
    gaq[q] = table + (size_t)cid[m0 + row]*H_ + (sch<<2);
  }
  const int f0 = tid, f1 = 256 + tid;
  const int r0 = f0 >> 2, s0 = ((f0 & 3) ^ ((f0 >> 3) & 3)) << 3;
  const int r1 = f1 >> 2, s1 = ((f1 & 3) ^ ((f1 >> 3) & 3)) << 3;
  const unsigned short* gb0 = Bw + (size_t)(n0 + r0)*H_ + s0;
  const unsigned short* gb1 = Bw + (size_t)(n0 + r1)*H_ + s1;

  f32x4 acc[4][4] = {};
  const int arow = (wr<<6) + (lane & 15);
  const int brow = (wc<<6) + (lane & 15);
  const int kg = lane >> 4;
  const int slb = ((kg ^ ((lane>>1)&3)) << 3);

  auto STAGE = [&](int buf, int k0){
    #pragma unroll
    for(int q=0;q<4;q++)
      gload_lds16(gaq[q] + k0, AsF[buf] + (q*256 + tid)*4);
    gload_lds16(gb0 + k0, Bs[buf] + (wave<<9));
    gload_lds16(gb1 + k0, Bs[buf] + 2048 + (wave<<9));
  };
  auto COMPUTE = [&](int buf){
    bf16x8 a[4], b[4];
    #pragma unroll
    for(int m=0;m<4;m++){
      const int R = arow + (m<<4);
      const int c1 = (2*kg) ^ (R&7), c2 = (2*kg+1) ^ (R&7);
      const f32x4 fa = *(const f32x4*)(AsF[buf] + R*32 + (c1<<2));
      const f32x4 fb = *(const f32x4*)(AsF[buf] + R*32 + (c2<<2));
      union { float f; unsigned int u; } z0,z1,z2,z3,z4,z5,z6,z7;
      z0.f=fa.x; z1.f=fa.y; z2.f=fa.z; z3.f=fa.w;
      z4.f=fb.x; z5.f=fb.y; z6.f=fb.z; z7.f=fb.w;
      union { unsigned int w[4]; bf16x8 v; } cv;
      cv.w[0] = (z1.u & 0xFFFF0000u) | (z0.u >> 16);
      cv.w[1] = (z3.u & 0xFFFF0000u) | (z2.u >> 16);
      cv.w[2] = (z5.u & 0xFFFF0000u) | (z4.u >> 16);
      cv.w[3] = (z7.u & 0xFFFF0000u) | (z6.u >> 16);
      a[m] = cv.v;
    }
    #pragma unroll
    for(int n=0;n<4;n++) b[n] = *(const bf16x8*)(Bs[buf] + (brow + (n<<4))*32 + slb);
    #pragma unroll
    for(int m=0;m<4;m++)
      #pragma unroll
      for(int n=0;n<4;n++)
        acc[m][n] = __builtin_amdgcn_mfma_f32_16x16x32_bf16(a[m], b[n], acc[m][n], 0,0,0);
  };

  const int NT = H_/32;   // 24
  STAGE(0, 0);
  STAGE(1, 32);
  for(int t=0; t<NT; ++t){
    const int tn = t+2;
    if(tn < NT) STAGE(tn%3, tn*32);
    if(t+2 < NT)      asm volatile("s_waitcnt vmcnt(12)" ::: "memory");
    else if(t+1 < NT) asm volatile("s_waitcnt vmcnt(6)"  ::: "memory");
    else              asm volatile("s_waitcnt vmcnt(0)"  ::: "memory");
    __builtin_amdgcn_s_barrier();
    COMPUTE(t%3);
    __builtin_amdgcn_s_barrier();
  }

  const int crow0 = (lane>>4) << 2;
  const int ccol  = lane & 15;
  float bia[4];
  #pragma unroll
  for(int n=0;n<4;n++) bia[n] = bias[n0 + (wc<<6) + (n<<4) + ccol];
  #pragma unroll
  for(int m=0;m<4;m++){
    const int gr0 = m0 + (wr<<6) + (m<<4) + crow0;
    #pragma unroll
    for(int j=0;j<4;j++){
      const size_t rbase = (size_t)(gr0 + j) * N1_;
      #pragma unroll
      for(int n=0;n<4;n++){
        float v = acc[m][n][j] + bia[n];
        v = fmaxf(v, 0.f);
        C[rbase + n0 + (wc<<6) + (n<<4) + ccol] = f2bf(v);
      }
    }
  }
}

// ---- K2: MFMA GEMM (bf16 A), BM=128; 3-buffer ring, counted vmcnt, raw s_barrier.
// L=4 loads/thread/STAGE: steady wait = vmcnt(8) = oldest tile only.
template<int KTOT, int NTOT>
__global__ __launch_bounds__(256) void k_gemm(
  const unsigned short* __restrict__ A, const unsigned short* __restrict__ Bw,
  const float* __restrict__ bias, const int* __restrict__ cnt,
  unsigned short* __restrict__ C)
{
  const int m0 = blockIdx.x << 7;
  if((m0 & (S_-1)) >= cnt[m0 >> 9]) return;
  __shared__ __align__(16) unsigned short As[3][128*32];
  __shared__ __align__(16) unsigned short Bs[3][128*32];
  const int tid = threadIdx.x;
  const int lane = tid & 63;
  const int wave = tid >> 6;
  const int wr = wave >> 1, wc = wave & 1;
  const int n0 = blockIdx.y << 7;

  const int f0 = tid, f1 = 256 + tid;
  const int r0 = f0 >> 2, s0 = ((f0 & 3) ^ ((f0 >> 3) & 3)) << 3;
  const int r1 = f1 >> 2, s1 = ((f1 & 3) ^ ((f1 >> 3) & 3)) << 3;
  const unsigned short* ga0 = A + (size_t)(m0 + r0)*KTOT + s0;
  const unsigned short* ga1 = A + (size_t)(m0 + r1)*KTOT + s1;
  const unsigned short* gb0 = Bw + (size_t)(n0 + r0)*KTOT + s0;
  const unsigned short* gb1 = Bw + (size_t)(n0 + r1)*KTOT + s1;

  f32x4 acc[4][4] = {};
  const int arow = (wr<<6) + (lane & 15);
  const int brow = (wc<<6) + (lane & 15);
  const int sl   = (((lane>>4) ^ ((lane>>1)&3)) << 3);

  auto STAGE = [&](int buf, int k0){
    gload_lds16(ga0 + k0, As[buf] + (wave<<9));
    gload_lds16(ga1 + k0, As[buf] + 2048 + (wave<<9));
    gload_lds16(gb0 + k0, Bs[buf] + (wave<<9));
    gload_lds16(gb1 + k0, Bs[buf] + 2048 + (wave<<9));
  };
  auto COMPUTE = [&](int buf){
    bf16x8 a[4], b[4];
    #pragma unroll
    for(int m=0;m<4;m++) a[m] = *(const bf16x8*)(As[buf] + (arow + (m<<4))*32 + sl);
    #pragma unroll
    for(int n=0;n<4;n++) b[n] = *(const bf16x8*)(Bs[buf] + (brow + (n<<4))*32 + sl);
    #pragma unroll
    for(int m=0;m<4;m++)
      #pragma unroll
      for(int n=0;n<4;n++)
        acc[m][n] = __builtin_amdgcn_mfma_f32_16x16x32_bf16(a[m], b[n], acc[m][n], 0,0,0);
  };

  const int NT = KTOT/32;
  STAGE(0, 0);
  STAGE(1, 32);
  for(int t=0; t<NT; ++t){
    const int tn = t+2;
    if(tn < NT) STAGE(tn%3, tn*32);
    if(t+2 < NT)      asm volatile("s_waitcnt vmcnt(8)" ::: "memory");
    else if(t+1 < NT) asm volatile("s_waitcnt vmcnt(4)" ::: "memory");
    else              asm volatile("s_waitcnt vmcnt(0)" ::: "memory");
    __builtin_amdgcn_s_barrier();
    COMPUTE(t%3);
    __builtin_amdgcn_s_barrier();
  }

  const int crow0 = (lane>>4) << 2;
  const int ccol  = lane & 15;
  float bia[4];
  #pragma unroll
  for(int n=0;n<4;n++) bia[n] = bias[n0 + (wc<<6) + (n<<4) + ccol];
  #pragma unroll
  for(int m=0;m<4;m++){
    const int gr0 = m0 + (wr<<6) + (m<<4) + crow0;
    #pragma unroll
    for(int j=0;j<4;j++){
      const size_t rbase = (size_t)(gr0 + j) * NTOT;
      #pragma unroll
      for(int n=0;n<4;n++){
        float v = acc[m][n][j] + bia[n];
        v = fmaxf(v, 0.f);
        C[rbase + n0 + (wc<<6) + (n<<4) + ccol] = f2bf(v);
      }
    }
  }
}

// ---- K3: attention scores, 32-row m-tiles (512 blocks), double-buffered (unchanged) ----
__global__ __launch_bounds__(256) void k_score(
  const unsigned short* __restrict__ A, const unsigned short* __restrict__ Bw,
  const float* __restrict__ ba1p, const float* __restrict__ Wa2p, const float* __restrict__ ba2,
  const int* __restrict__ cnt, float* __restrict__ scoresC)
{
  const int m0 = blockIdx.x << 5;
  if((m0 & (S_-1)) >= cnt[m0 >> 9]) return;
  __shared__ __align__(16) unsigned short As[2][32*32];
  __shared__ __align__(16) unsigned short Bs[2][128*32];
  __shared__ float sums[32][4];
  const int tid = threadIdx.x;
  const int lane = tid & 63;
  const int wave = tid >> 6;

  const int fa = tid, ra = fa >> 2, sa = ((fa & 3) ^ ((fa >> 3) & 3)) << 3;
  const unsigned short* gaS = A + (size_t)(m0 + ra)*H_ + sa;
  const int f0 = tid, f1 = 256 + tid;
  const int r0 = f0 >> 2, s0 = ((f0 & 3) ^ ((f0 >> 3) & 3)) << 3;
  const int r1 = f1 >> 2, s1 = ((f1 & 3) ^ ((f1 >> 3) & 3)) << 3;
  const unsigned short* gb0 = Bw + (size_t)r0*H_ + s0;
  const unsigned short* gb1 = Bw + (size_t)r1*H_ + s1;

  f32x4 acc[2][2] = {};
  const int sl = (((lane>>4) ^ ((lane>>1)&3)) << 3);

  auto STAGE = [&](int buf, int k0){
    if(wave < 2) gload_lds16(gaS + k0, As[buf] + (wave<<9));
    gload_lds16(gb0 + k0, Bs[buf] + (wave<<9));
    gload_lds16(gb1 + k0, Bs[buf] + 2048 + (wave<<9));
  };
  auto COMPUTE = [&](int buf){
    bf16x8 a[2], b[2];
    #pragma unroll
    for(int m=0;m<2;m++) a[m] = *(const bf16x8*)(As[buf] + ((lane&15) + (m<<4))*32 + sl);
    #pragma unroll
    for(int n=0;n<2;n++) b[n] = *(const bf16x8*)(Bs[buf] + ((wave<<5) + (n<<4) + (lane&15))*32 + sl);
    #pragma unroll
    for(int m=0;m<2;m++)
      #pragma unroll
      for(int n=0;n<2;n++)
        acc[m][n] = __builtin_amdgcn_mfma_f32_16x16x32_bf16(a[m], b[n], acc[m][n], 0,0,0);
  };

  STAGE(0, 0);
  __syncthreads();
  for(int k0 = 0; k0 < H_; k0 += 64){
    if(k0+32 < H_) STAGE(1, k0+32);
    COMPUTE(0);
    __syncthreads();
    if(k0+64 < H_) STAGE(0, k0+64);
    COMPUTE(1);
    __syncthreads();
  }

  float ps[2][4] = {{0.f,0.f,0.f,0.f},{0.f,0.f,0.f,0.f}};
  #pragma unroll
  for(int n=0;n<2;n++){
    const int c = (wave<<5) + (n<<4) + (lane & 15);
    const float w2 = Wa2p[c], bb = ba1p[c];
    #pragma unroll
    for(int m=0;m<2;m++)
      #pragma unroll
      for(int j=0;j<4;j++)
        ps[m][j] = fmaf(tanhf(acc[m][n][j] + bb), w2, ps[m][j]);
  }
  #pragma unroll
  for(int msk=1; msk<16; msk<<=1)
    #pragma unroll
    for(int m=0;m<2;m++)
      #pragma unroll
      for(int j=0;j<4;j++)
        ps[m][j] += __shfl_xor(ps[m][j], msk, 64);
  if((lane & 15) == 0){
    #pragma unroll
    for(int m=0;m<2;m++)
      #pragma unroll
      for(int j=0;j<4;j++)
        sums[(m<<4) + ((lane>>4)<<2) + j][wave] = ps[m][j];
  }
  __syncthreads();
  if(tid < 32)
    scoresC[m0 + tid] = sums[tid][0] + sums[tid][1] + sums[tid][2] + sums[tid][3] + ba2[0];
}

// ---- K4: fused softmax + weighted sum + final predict (atomicAdd into out).
//      32 batches x 16 chunks of 32 rows. ch==0 block also adds hiddens-term + bias. ----
__global__ __launch_bounds__(256) void k_tail(
  const float* __restrict__ scoresC, const int* __restrict__ cnt,
  const unsigned short* __restrict__ wh, const float* __restrict__ hiddens,
  const float* __restrict__ Wa2, const float* __restrict__ ba1, const float* __restrict__ ba2,
  const float* __restrict__ Wl, const float* __restrict__ bl,
  float* __restrict__ out)
{
  const int b = blockIdx.x >> 4, ch = blockIdx.x & 15, tid = threadIdx.x;
  const int n = cnt[b];
  const int j0 = ch << 5;
  const int nch = min(n - j0, 32);
  __shared__ float red[256];

  if(ch == 0){
    const float* hid = hiddens + (size_t)b * S_ * H_;
    for(int c=0;c<3;c++){
      float p = 0.f;
      #pragma unroll
      for(int r=0;r<3;r++){
        const int h = tid + (r<<8);
        p = fmaf(hid[h], Wl[c*1536 + h], p);
      }
      red[tid]=p; __syncthreads();
      for(int st=128; st>0; st>>=1){ if(tid<st) red[tid]+=red[tid+st]; __syncthreads(); }
      if(tid==0) atomicAdd(out + b*3 + c, red[0] + bl[c]);
      __syncthreads();
    }
  }
  if(nch <= 0) return;

  __shared__ float sw[32];
  red[tid] = (tid < 100) ? Wa2[tid]*tanhf(ba1[tid]) : 0.f;
  __syncthreads();
  for(int st=128; st>0; st>>=1){ if(tid<st) red[tid]+=red[tid+st]; __syncthreads(); }
  const float c0 = red[0] + ba2[0];
  __syncthreads();
  const float s1 = (tid     < n) ? scoresC[b*S_ + tid      ] : -1e30f;
  const float s2 = (tid+256 < n) ? scoresC[b*S_ + tid + 256] : -1e30f;
  float lm = fmaxf(s1, s2);
  if(tid==0 && n < 511) lm = fmaxf(lm, c0);
  red[tid] = lm; __syncthreads();
  for(int st=128; st>0; st>>=1){ if(tid<st) red[tid]=fmaxf(red[tid], red[tid+st]); __syncthreads(); }
  const float mx = red[0]; __syncthreads();
  const float e1 = (tid     < n) ? __expf(s1-mx) : 0.f;
  const float e2 = (tid+256 < n) ? __expf(s2-mx) : 0.f;
  red[tid] = e1+e2; __syncthreads();
  for(int st=128; st>0; st>>=1){ if(tid<st) red[tid]+=red[tid+st]; __syncthreads(); }
  const float denom = red[0] + (float)(511 - n) * __expf(c0 - mx);
  const float inv = 1.f/denom;
  if(tid < 32){
    const int j = j0 + tid;
    sw[tid] = (j < n) ? __expf(scoresC[b*S_+j]-mx)*inv : 0.f;
  }
  __syncthreads();

  float a0=0.f, a1=0.f, a2=0.f, a3=0.f;
  if(tid < 192){
    const unsigned short* wp = wh + ((size_t)(b*S_ + j0))*H_ + (tid<<2);
    #pragma unroll 4
    for(int t=0;t<nch;t++){
      const float wv = sw[t];
      const ushort4 v = *(const ushort4*)(wp + (size_t)t*H_);
      a0 = fmaf(wv, bf2f(v.x), a0);
      a1 = fmaf(wv, bf2f(v.y), a1);
      a2 = fmaf(wv, bf2f(v.z), a2);
      a3 = fmaf(wv, bf2f(v.w), a3);
    }
  }
  for(int c=0;c<3;c++){
    float p = 0.f;
    if(tid < 192){
      const float4 wl = *(const float4*)(Wl + c*1536 + 768 + (tid<<2));
      p = a0*wl.x + a1*wl.y + a2*wl.z + a3*wl.w;
    }
    red[tid]=p; __syncthreads();
    for(int st=128; st>0; st>>=1){ if(tid<st) red[tid]+=red[tid+st]; __syncthreads(); }
    if(tid==0) atomicAdd(out + b*3 + c, red[0]);
    __syncthreads();
  }
}

extern "C" void kernel_launch(void* const* d_in, const int* in_sizes, int n_in,
                              void* d_out, int out_size, void* d_ws, size_t ws_size,
                              hipStream_t stream)
{
  const float* hiddens = (const float*)d_in[0];
  const int*   ids     = (const int*)d_in[1];
  const void*  in_tab  = d_in[2];
  const float* table   = (const float*)d_in[3];
  const float* W1      = (const float*)d_in[4];
  const float* b1      = (const float*)d_in[5];
  const float* W2      = (const float*)d_in[6];
  const float* b2      = (const float*)d_in[7];
  const float* Wa1     = (const float*)d_in[8];
  const float* ba1     = (const float*)d_in[9];
  const float* Wa2     = (const float*)d_in[10];
  const float* ba2     = (const float*)d_in[11];
  const float* Wl      = (const float*)d_in[12];
  const float* bl      = (const float*)d_in[13];
  float* out = (float*)d_out;

  char* w = (char*)d_ws;
  unsigned short* wh    = (unsigned short*)w;                // 25165824
  unsigned short* x     = (unsigned short*)(w + 25165824);   // 16777216
  unsigned short* W1bf  = (unsigned short*)(w + 41943040);   // 786432
  unsigned short* W2bf  = (unsigned short*)(w + 42729472);   // 786432
  unsigned short* Wa1bf = (unsigned short*)(w + 43515904);   // 196608
  float* Wa2p    = (float*)(w + 43712512);                   // 512
  float* ba1p    = (float*)(w + 43713024);                   // 512
  float* scoresC = (float*)(w + 43713536);                   // 65536
  int*   cid     = (int*)  (w + 43779072);                   // 65536
  int*   cnt     = (int*)  (w + 43844608);                   // 128

  hipLaunchKernelGGL(k_prep,   dim3(768), dim3(256), 0, stream, in_tab, ids,
                     W1, W2, Wa1, Wa2, ba1, W1bf, W2bf, Wa1bf, Wa2p, ba1p, cid, cnt, out);
  hipLaunchKernelGGL(k_gemm1g, dim3(128, 4), dim3(256), 0, stream, table, cid, W1bf, b1, cnt, x);
  hipLaunchKernelGGL((k_gemm<N1_, H_>), dim3(128, 6), dim3(256), 0, stream, x, W2bf, b2, cnt, wh);
  hipLaunchKernelGGL(k_score,  dim3(512), dim3(256), 0, stream, wh, Wa1bf, ba1p, Wa2p, ba2, cnt, scoresC);
  hipLaunchKernelGGL(k_tail,   dim3(512), dim3(256), 0, stream, scoresC, cnt, wh, hiddens, Wa2, ba1, ba2, Wl, bl, out);
}

// Round 13
// 78.285 us; speedup vs baseline: 1.0565x; 1.0565x over previous
//
#include <hip/hip_runtime.h>
#include <stdint.h>
#include <math.h>

#define B_ 32
#define S_ 512
#define H_ 768
#define V_ 30522
#define M_ (B_*S_)   // 16384
#define N1_ 512

typedef __attribute__((ext_vector_type(8))) short bf16x8;
typedef __attribute__((ext_vector_type(4))) float f32x4;

__device__ __forceinline__ float bf2f(unsigned short u){
  union { unsigned int u; float f; } c; c.u = ((unsigned int)u)<<16; return c.f;
}
__device__ __forceinline__ unsigned short f2bf(float f){
  union { float f; unsigned int u; } c; c.f=f;
  unsigned int u = c.u + 0x7FFFu + ((c.u>>16)&1u);
  return (unsigned short)(u>>16);
}
__device__ __forceinline__ bool tbl_get(const void* t, int id, int flag){
  if(flag==1) return ((const int*)t)[id]!=0;
  if(flag==2) return ((const unsigned int*)t)[id]!=0u;   // f32 stored 0.0/1.0
  return ((const unsigned char*)t)[id]!=0;
}
__device__ __forceinline__ void gload_lds16(const void* g, void* l){
  __builtin_amdgcn_global_load_lds(
    (const __attribute__((address_space(1))) void*)g,
    (__attribute__((address_space(3))) void*)l, 16, 0, 0);
}

// ---- K0: blocks 0-31: per-batch mask+scan -> cid/cnt; blocks 32+: weight conversion.
//      Block 32 also zeroes the output (atomic-accumulated by k_tail later in stream order).
__global__ __launch_bounds__(256) void k_prep(const void* __restrict__ in_table,
  const int* __restrict__ ids,
  const float* __restrict__ W1, const float* __restrict__ W2,
  const float* __restrict__ Wa1, const float* __restrict__ Wa2, const float* __restrict__ ba1,
  unsigned short* __restrict__ W1bf, unsigned short* __restrict__ W2bf,
  unsigned short* __restrict__ Wa1bf, float* __restrict__ Wa2p, float* __restrict__ ba1p,
  int* __restrict__ cid, int* __restrict__ cnt, float* __restrict__ out)
{
  const int blk = blockIdx.x;
  const int t = threadIdx.x;
  if(blk < 32){
    __shared__ int sh[512];
    __shared__ int sflag;
    if(t < 64){
      const int v = ((const int*)in_table)[t];
      const unsigned int u = (unsigned int)v;
      const unsigned long long b01 = __ballot(v==0 || v==1);
      const unsigned long long bfl = __ballot(u==0u || u==0x3F800000u);
      if(t==0) sflag = (~b01==0ull) ? 1 : ((~bfl==0ull) ? 2 : 0);
    }
    __syncthreads();
    const int flag = sflag;
    const int m0 = blk*S_ + t, m1 = m0 + 256;
    const int id0 = ids[m0], id1 = ids[m1];
    const int mk0 = ((t!=0) && tbl_get(in_table, id0, flag)) ? 1 : 0;
    const int mk1 = tbl_get(in_table, id1, flag) ? 1 : 0;
    sh[t] = mk0; sh[t+256] = mk1;
    __syncthreads();
    for(int off=1; off<512; off<<=1){
      const int a0 = (t >= off) ? sh[t-off] : 0;
      const int a1 = (t+256 >= off) ? sh[t+256-off] : 0;
      __syncthreads();
      sh[t] += a0; sh[t+256] += a1;
      __syncthreads();
    }
    const int total = sh[511];
    const int r0 = sh[t] - mk0;
    const int r1 = sh[t+256] - mk1;
    if(t >= total)     cid[blk*S_ + t]       = 0;
    if(t+256 >= total) cid[blk*S_ + t + 256] = 0;
    if(mk0) cid[blk*S_ + r0] = id0;
    if(mk1) cid[blk*S_ + r1] = id1;
    if(t==0) cnt[blk] = total;
  } else {
    if(blk == 32 && t < 96) out[t] = 0.f;
    const int g = (blk-32)*256 + t, st = (gridDim.x-32)*256;
    for(int i=g;i<512*H_;i+=st) W1bf[i]=f2bf(W1[i]);
    for(int i=g;i<H_*512;i+=st) W2bf[i]=f2bf(W2[i]);
    for(int i=g;i<128*H_;i+=st) Wa1bf[i] = (i<100*H_)? f2bf(Wa1[i]) : (unsigned short)0;
    if(g < 128){ Wa2p[g] = (g<100)? Wa2[g] : 0.f; ba1p[g] = (g<100)? ba1[g] : 0.f; }
  }
}

// ---- K1: gather-fused MFMA GEMM1: x = relu(table[cid[.]] . W1^T + b1), bf16 out ----
// BM=128, double-buffered 2-phase; A staged f32 from table, packed to bf16 in regs.
__global__ __launch_bounds__(256) void k_gemm1g(
  const float* __restrict__ table, const int* __restrict__ cid,
  const unsigned short* __restrict__ Bw, const float* __restrict__ bias,
  const int* __restrict__ cnt, unsigned short* __restrict__ C)
{
  const int m0 = blockIdx.x << 7;
  if((m0 & (S_-1)) >= cnt[m0 >> 9]) return;
  __shared__ __align__(16) float AsF[2][128*32];
  __shared__ __align__(16) unsigned short Bs[2][128*32];
  const int tid = threadIdx.x;
  const int lane = tid & 63;
  const int wave = tid >> 6;
  const int wr = wave >> 1, wc = wave & 1;
  const int n0 = blockIdx.y << 7;

  const float* gaq[4];
  #pragma unroll
  for(int q=0;q<4;q++){
    const int s = q*256 + tid;
    const int row = s >> 3, ch = s & 7;
    const int sch = ch ^ (row & 7);
    gaq[q] = table + (size_t)cid[m0 + row]*H_ + (sch<<2);
  }
  const int f0 = tid, f1 = 256 + tid;
  const int r0 = f0 >> 2, s0 = ((f0 & 3) ^ ((f0 >> 3) & 3)) << 3;
  const int r1 = f1 >> 2, s1 = ((f1 & 3) ^ ((f1 >> 3) & 3)) << 3;
  const unsigned short* gb0 = Bw + (size_t)(n0 + r0)*H_ + s0;
  const unsigned short* gb1 = Bw + (size_t)(n0 + r1)*H_ + s1;

  f32x4 acc[4][4] = {};
  const int arow = (wr<<6) + (lane & 15);
  const int brow = (wc<<6) + (lane & 15);
  const int kg = lane >> 4;
  const int slb = ((kg ^ ((lane>>1)&3)) << 3);

  auto STAGE = [&](int buf, int k0){
    #pragma unroll
    for(int q=0;q<4;q++)
      gload_lds16(gaq[q] + k0, AsF[buf] + (q*256 + tid)*4);
    gload_lds16(gb0 + k0, Bs[buf] + (wave<<9));
    gload_lds16(gb1 + k0, Bs[buf] + 2048 + (wave<<9));
  };
  auto COMPUTE = [&](int buf){
    bf16x8 a[4], b[4];
    #pragma unroll
    for(int m=0;m<4;m++){
      const int R = arow + (m<<4);
      const int c1 = (2*kg) ^ (R&7), c2 = (2*kg+1) ^ (R&7);
      const f32x4 fa = *(const f32x4*)(AsF[buf] + R*32 + (c1<<2));
      const f32x4 fb = *(const f32x4*)(AsF[buf] + R*32 + (c2<<2));
      union { float f; unsigned int u; } z0,z1,z2,z3,z4,z5,z6,z7;
      z0.f=fa.x; z1.f=fa.y; z2.f=fa.z; z3.f=fa.w;
      z4.f=fb.x; z5.f=fb.y; z6.f=fb.z; z7.f=fb.w;
      union { unsigned int w[4]; bf16x8 v; } cv;
      cv.w[0] = (z1.u & 0xFFFF0000u) | (z0.u >> 16);
      cv.w[1] = (z3.u & 0xFFFF0000u) | (z2.u >> 16);
      cv.w[2] = (z5.u & 0xFFFF0000u) | (z4.u >> 16);
      cv.w[3] = (z7.u & 0xFFFF0000u) | (z6.u >> 16);
      a[m] = cv.v;
    }
    #pragma unroll
    for(int n=0;n<4;n++) b[n] = *(const bf16x8*)(Bs[buf] + (brow + (n<<4))*32 + slb);
    #pragma unroll
    for(int m=0;m<4;m++)
      #pragma unroll
      for(int n=0;n<4;n++)
        acc[m][n] = __builtin_amdgcn_mfma_f32_16x16x32_bf16(a[m], b[n], acc[m][n], 0,0,0);
  };

  STAGE(0, 0);
  __syncthreads();
  for(int k0 = 0; k0 < H_; k0 += 64){
    if(k0+32 < H_) STAGE(1, k0+32);
    COMPUTE(0);
    __syncthreads();
    if(k0+64 < H_) STAGE(0, k0+64);
    COMPUTE(1);
    __syncthreads();
  }

  const int crow0 = (lane>>4) << 2;
  const int ccol  = lane & 15;
  float bia[4];
  #pragma unroll
  for(int n=0;n<4;n++) bia[n] = bias[n0 + (wc<<6) + (n<<4) + ccol];
  #pragma unroll
  for(int m=0;m<4;m++){
    const int gr0 = m0 + (wr<<6) + (m<<4) + crow0;
    #pragma unroll
    for(int j=0;j<4;j++){
      const size_t rbase = (size_t)(gr0 + j) * N1_;
      #pragma unroll
      for(int n=0;n<4;n++){
        float v = acc[m][n][j] + bia[n];
        v = fmaxf(v, 0.f);
        C[rbase + n0 + (wc<<6) + (n<<4) + ccol] = f2bf(v);
      }
    }
  }
}

// ---- K2: MFMA GEMM (bf16 A), BM=128, double-buffered 2-phase K-loop ----
template<int KTOT, int NTOT>
__global__ __launch_bounds__(256) void k_gemm(
  const unsigned short* __restrict__ A, const unsigned short* __restrict__ Bw,
  const float* __restrict__ bias, const int* __restrict__ cnt,
  unsigned short* __restrict__ C)
{
  const int m0 = blockIdx.x << 7;
  if((m0 & (S_-1)) >= cnt[m0 >> 9]) return;
  __shared__ __align__(16) unsigned short As[2][128*32];
  __shared__ __align__(16) unsigned short Bs[2][128*32];
  const int tid = threadIdx.x;
  const int lane = tid & 63;
  const int wave = tid >> 6;
  const int wr = wave >> 1, wc = wave & 1;
  const int n0 = blockIdx.y << 7;

  const int f0 = tid, f1 = 256 + tid;
  const int r0 = f0 >> 2, s0 = ((f0 & 3) ^ ((f0 >> 3) & 3)) << 3;
  const int r1 = f1 >> 2, s1 = ((f1 & 3) ^ ((f1 >> 3) & 3)) << 3;
  const unsigned short* ga0 = A + (size_t)(m0 + r0)*KTOT + s0;
  const unsigned short* ga1 = A + (size_t)(m0 + r1)*KTOT + s1;
  const unsigned short* gb0 = Bw + (size_t)(n0 + r0)*KTOT + s0;
  const unsigned short* gb1 = Bw + (size_t)(n0 + r1)*KTOT + s1;

  f32x4 acc[4][4] = {};
  const int arow = (wr<<6) + (lane & 15);
  const int brow = (wc<<6) + (lane & 15);
  const int sl   = (((lane>>4) ^ ((lane>>1)&3)) << 3);

  auto STAGE = [&](int buf, int k0){
    gload_lds16(ga0 + k0, As[buf] + (wave<<9));
    gload_lds16(ga1 + k0, As[buf] + 2048 + (wave<<9));
    gload_lds16(gb0 + k0, Bs[buf] + (wave<<9));
    gload_lds16(gb1 + k0, Bs[buf] + 2048 + (wave<<9));
  };
  auto COMPUTE = [&](int buf){
    bf16x8 a[4], b[4];
    #pragma unroll
    for(int m=0;m<4;m++) a[m] = *(const bf16x8*)(As[buf] + (arow + (m<<4))*32 + sl);
    #pragma unroll
    for(int n=0;n<4;n++) b[n] = *(const bf16x8*)(Bs[buf] + (brow + (n<<4))*32 + sl);
    #pragma unroll
    for(int m=0;m<4;m++)
      #pragma unroll
      for(int n=0;n<4;n++)
        acc[m][n] = __builtin_amdgcn_mfma_f32_16x16x32_bf16(a[m], b[n], acc[m][n], 0,0,0);
  };

  STAGE(0, 0);
  __syncthreads();
  for(int k0 = 0; k0 < KTOT; k0 += 64){
    if(k0+32 < KTOT) STAGE(1, k0+32);
    COMPUTE(0);
    __syncthreads();
    if(k0+64 < KTOT) STAGE(0, k0+64);
    COMPUTE(1);
    __syncthreads();
  }

  const int crow0 = (lane>>4) << 2;
  const int ccol  = lane & 15;
  float bia[4];
  #pragma unroll
  for(int n=0;n<4;n++) bia[n] = bias[n0 + (wc<<6) + (n<<4) + ccol];
  #pragma unroll
  for(int m=0;m<4;m++){
    const int gr0 = m0 + (wr<<6) + (m<<4) + crow0;
    #pragma unroll
    for(int j=0;j<4;j++){
      const size_t rbase = (size_t)(gr0 + j) * NTOT;
      #pragma unroll
      for(int n=0;n<4;n++){
        float v = acc[m][n][j] + bia[n];
        v = fmaxf(v, 0.f);
        C[rbase + n0 + (wc<<6) + (n<<4) + ccol] = f2bf(v);
      }
    }
  }
}

// ---- K3: attention scores, 32-row m-tiles (512 blocks), double-buffered ----
__global__ __launch_bounds__(256) void k_score(
  const unsigned short* __restrict__ A, const unsigned short* __restrict__ Bw,
  const float* __restrict__ ba1p, const float* __restrict__ Wa2p, const float* __restrict__ ba2,
  const int* __restrict__ cnt, float* __restrict__ scoresC)
{
  const int m0 = blockIdx.x << 5;
  if((m0 & (S_-1)) >= cnt[m0 >> 9]) return;
  __shared__ __align__(16) unsigned short As[2][32*32];
  __shared__ __align__(16) unsigned short Bs[2][128*32];
  __shared__ float sums[32][4];
  const int tid = threadIdx.x;
  const int lane = tid & 63;
  const int wave = tid >> 6;

  const int fa = tid, ra = fa >> 2, sa = ((fa & 3) ^ ((fa >> 3) & 3)) << 3;
  const unsigned short* gaS = A + (size_t)(m0 + ra)*H_ + sa;
  const int f0 = tid, f1 = 256 + tid;
  const int r0 = f0 >> 2, s0 = ((f0 & 3) ^ ((f0 >> 3) & 3)) << 3;
  const int r1 = f1 >> 2, s1 = ((f1 & 3) ^ ((f1 >> 3) & 3)) << 3;
  const unsigned short* gb0 = Bw + (size_t)r0*H_ + s0;
  const unsigned short* gb1 = Bw + (size_t)r1*H_ + s1;

  f32x4 acc[2][2] = {};
  const int sl = (((lane>>4) ^ ((lane>>1)&3)) << 3);

  auto STAGE = [&](int buf, int k0){
    if(wave < 2) gload_lds16(gaS + k0, As[buf] + (wave<<9));
    gload_lds16(gb0 + k0, Bs[buf] + (wave<<9));
    gload_lds16(gb1 + k0, Bs[buf] + 2048 + (wave<<9));
  };
  auto COMPUTE = [&](int buf){
    bf16x8 a[2], b[2];
    #pragma unroll
    for(int m=0;m<2;m++) a[m] = *(const bf16x8*)(As[buf] + ((lane&15) + (m<<4))*32 + sl);
    #pragma unroll
    for(int n=0;n<2;n++) b[n] = *(const bf16x8*)(Bs[buf] + ((wave<<5) + (n<<4) + (lane&15))*32 + sl);
    #pragma unroll
    for(int m=0;m<2;m++)
      #pragma unroll
      for(int n=0;n<2;n++)
        acc[m][n] = __builtin_amdgcn_mfma_f32_16x16x32_bf16(a[m], b[n], acc[m][n], 0,0,0);
  };

  STAGE(0, 0);
  __syncthreads();
  for(int k0 = 0; k0 < H_; k0 += 64){
    if(k0+32 < H_) STAGE(1, k0+32);
    COMPUTE(0);
    __syncthreads();
    if(k0+64 < H_) STAGE(0, k0+64);
    COMPUTE(1);
    __syncthreads();
  }

  float ps[2][4] = {{0.f,0.f,0.f,0.f},{0.f,0.f,0.f,0.f}};
  #pragma unroll
  for(int n=0;n<2;n++){
    const int c = (wave<<5) + (n<<4) + (lane & 15);
    const float w2 = Wa2p[c], bb = ba1p[c];
    #pragma unroll
    for(int m=0;m<2;m++)
      #pragma unroll
      for(int j=0;j<4;j++)
        ps[m][j] = fmaf(tanhf(acc[m][n][j] + bb), w2, ps[m][j]);
  }
  #pragma unroll
  for(int msk=1; msk<16; msk<<=1)
    #pragma unroll
    for(int m=0;m<2;m++)
      #pragma unroll
      for(int j=0;j<4;j++)
        ps[m][j] += __shfl_xor(ps[m][j], msk, 64);
  if((lane & 15) == 0){
    #pragma unroll
    for(int m=0;m<2;m++)
      #pragma unroll
      for(int j=0;j<4;j++)
        sums[(m<<4) + ((lane>>4)<<2) + j][wave] = ps[m][j];
  }
  __syncthreads();
  if(tid < 32)
    scoresC[m0 + tid] = sums[tid][0] + sums[tid][1] + sums[tid][2] + sums[tid][3] + ba2[0];
}

// ---- K4: fused softmax + weighted sum + final predict (atomicAdd into out).
//      32 batches x 16 chunks of 32 rows. ch==0 block also adds hiddens-term + bias. ----
__global__ __launch_bounds__(256) void k_tail(
  const float* __restrict__ scoresC, const int* __restrict__ cnt,
  const unsigned short* __restrict__ wh, const float* __restrict__ hiddens,
  const float* __restrict__ Wa2, const float* __restrict__ ba1, const float* __restrict__ ba2,
  const float* __restrict__ Wl, const float* __restrict__ bl,
  float* __restrict__ out)
{
  const int b = blockIdx.x >> 4, ch = blockIdx.x & 15, tid = threadIdx.x;
  const int n = cnt[b];
  const int j0 = ch << 5;
  const int nch = min(n - j0, 32);
  __shared__ float red[256];

  if(ch == 0){
    const float* hid = hiddens + (size_t)b * S_ * H_;
    for(int c=0;c<3;c++){
      float p = 0.f;
      #pragma unroll
      for(int r=0;r<3;r++){
        const int h = tid + (r<<8);
        p = fmaf(hid[h], Wl[c*1536 + h], p);
      }
      red[tid]=p; __syncthreads();
      for(int st=128; st>0; st>>=1){ if(tid<st) red[tid]+=red[tid+st]; __syncthreads(); }
      if(tid==0) atomicAdd(out + b*3 + c, red[0] + bl[c]);
      __syncthreads();
    }
  }
  if(nch <= 0) return;

  __shared__ float sw[32];
  red[tid] = (tid < 100) ? Wa2[tid]*tanhf(ba1[tid]) : 0.f;
  __syncthreads();
  for(int st=128; st>0; st>>=1){ if(tid<st) red[tid]+=red[tid+st]; __syncthreads(); }
  const float c0 = red[0] + ba2[0];
  __syncthreads();
  const float s1 = (tid     < n) ? scoresC[b*S_ + tid      ] : -1e30f;
  const float s2 = (tid+256 < n) ? scoresC[b*S_ + tid + 256] : -1e30f;
  float lm = fmaxf(s1, s2);
  if(tid==0 && n < 511) lm = fmaxf(lm, c0);
  red[tid] = lm; __syncthreads();
  for(int st=128; st>0; st>>=1){ if(tid<st) red[tid]=fmaxf(red[tid], red[tid+st]); __syncthreads(); }
  const float mx = red[0]; __syncthreads();
  const float e1 = (tid     < n) ? __expf(s1-mx) : 0.f;
  const float e2 = (tid+256 < n) ? __expf(s2-mx) : 0.f;
  red[tid] = e1+e2; __syncthreads();
  for(int st=128; st>0; st>>=1){ if(tid<st) red[tid]+=red[tid+st]; __syncthreads(); }
  const float denom = red[0] + (float)(511 - n) * __expf(c0 - mx);
  const float inv = 1.f/denom;
  if(tid < 32){
    const int j = j0 + tid;
    sw[tid] = (j < n) ? __expf(scoresC[b*S_+j]-mx)*inv : 0.f;
  }
  __syncthreads();

  float a0=0.f, a1=0.f, a2=0.f, a3=0.f;
  if(tid < 192){
    const unsigned short* wp = wh + ((size_t)(b*S_ + j0))*H_ + (tid<<2);
    #pragma unroll 4
    for(int t=0;t<nch;t++){
      const float wv = sw[t];
      const ushort4 v = *(const ushort4*)(wp + (size_t)t*H_);
      a0 = fmaf(wv, bf2f(v.x), a0);
      a1 = fmaf(wv, bf2f(v.y), a1);
      a2 = fmaf(wv, bf2f(v.z), a2);
      a3 = fmaf(wv, bf2f(v.w), a3);
    }
  }
  for(int c=0;c<3;c++){
    float p = 0.f;
    if(tid < 192){
      const float4 wl = *(const float4*)(Wl + c*1536 + 768 + (tid<<2));
      p = a0*wl.x + a1*wl.y + a2*wl.z + a3*wl.w;
    }
    red[tid]=p; __syncthreads();
    for(int st=128; st>0; st>>=1){ if(tid<st) red[tid]+=red[tid+st]; __syncthreads(); }
    if(tid==0) atomicAdd(out + b*3 + c, red[0]);
    __syncthreads();
  }
}

extern "C" void kernel_launch(void* const* d_in, const int* in_sizes, int n_in,
                              void* d_out, int out_size, void* d_ws, size_t ws_size,
                              hipStream_t stream)
{
  const float* hiddens = (const float*)d_in[0];
  const int*   ids     = (const int*)d_in[1];
  const void*  in_tab  = d_in[2];
  const float* table   = (const float*)d_in[3];
  const float* W1      = (const float*)d_in[4];
  const float* b1      = (const float*)d_in[5];
  const float* W2      = (const float*)d_in[6];
  const float* b2      = (const float*)d_in[7];
  const float* Wa1     = (const float*)d_in[8];
  const float* ba1     = (const float*)d_in[9];
  const float* Wa2     = (const float*)d_in[10];
  const float* ba2     = (const float*)d_in[11];
  const float* Wl      = (const float*)d_in[12];
  const float* bl      = (const float*)d_in[13];
  float* out = (float*)d_out;

  char* w = (char*)d_ws;
  unsigned short* wh    = (unsigned short*)w;                // 25165824
  unsigned short* x     = (unsigned short*)(w + 25165824);   // 16777216
  unsigned short* W1bf  = (unsigned short*)(w + 41943040);   // 786432
  unsigned short* W2bf  = (unsigned short*)(w + 42729472);   // 786432
  unsigned short* Wa1bf = (unsigned short*)(w + 43515904);   // 196608
  float* Wa2p    = (float*)(w + 43712512);                   // 512
  float* ba1p    = (float*)(w + 43713024);                   // 512
  float* scoresC = (float*)(w + 43713536);                   // 65536
  int*   cid     = (int*)  (w + 43779072);                   // 65536
  int*   cnt     = (int*)  (w + 43844608);                   // 128

  hipLaunchKernelGGL(k_prep,   dim3(768), dim3(256), 0, stream, in_tab, ids,
                     W1, W2, Wa1, Wa2, ba1, W1bf, W2bf, Wa1bf, Wa2p, ba1p, cid, cnt, out);
  hipLaunchKernelGGL(k_gemm1g, dim3(128, 4), dim3(256), 0, stream, table, cid, W1bf, b1, cnt, x);
  hipLaunchKernelGGL((k_gemm<N1_, H_>), dim3(128, 6), dim3(256), 0, stream, x, W2bf, b2, cnt, wh);
  hipLaunchKernelGGL(k_score,  dim3(512), dim3(256), 0, stream, wh, Wa1bf, ba1p, Wa2p, ba2, cnt, scoresC);
  hipLaunchKernelGGL(k_tail,   dim3(512), dim3(256), 0, stream, scoresC, cnt, wh, hiddens, Wa2, ba1, ba2, Wl, bl, out);
}